// Round 1
// baseline (1927.638 us; speedup 1.0000x reference)
//
#include <hip/hip_runtime.h>
#include <math.h>

// ---------------- CSR build ----------------

__global__ void k_hist(const int* __restrict__ dst, int* __restrict__ deg, int e) {
    int t = blockIdx.x * 256 + threadIdx.x;
    if (t < e) atomicAdd(&deg[dst[t]], 1);
}

__global__ void k_scan1(const int* __restrict__ deg, int* __restrict__ tmp,
                        int* __restrict__ bsum, int n) {
    __shared__ int s[1024];
    int t = threadIdx.x;
    int g = blockIdx.x * 1024 + t;
    int v = (g < n) ? deg[g] : 0;
    s[t] = v;
    __syncthreads();
    for (int off = 1; off < 1024; off <<= 1) {
        int u = (t >= off) ? s[t - off] : 0;
        __syncthreads();
        s[t] += u;
        __syncthreads();
    }
    if (g < n) tmp[g] = s[t];
    if (t == 1023) bsum[blockIdx.x] = s[t];
}

__global__ void k_scan2(int* bsum, int nb) {
    // single thread exclusive scan over block sums (nb ~ 49)
    int acc = 0;
    for (int b = 0; b < nb; ++b) { int v = bsum[b]; bsum[b] = acc; acc += v; }
}

__global__ void k_scan3(const int* __restrict__ deg, const int* __restrict__ tmp,
                        const int* __restrict__ bsum, int* __restrict__ rowptr,
                        int* __restrict__ cursor, int n) {
    int g = blockIdx.x * 256 + threadIdx.x;
    if (g < n) {
        int incl = tmp[g] + bsum[g >> 10];
        rowptr[g + 1] = incl;
        cursor[g] = incl - deg[g];
        if (g == 0) rowptr[0] = 0;
    }
}

__global__ void k_scatter(const int* __restrict__ src, const int* __restrict__ dst,
                          int* __restrict__ cursor, int* __restrict__ csr, int e) {
    int t = blockIdx.x * 256 + threadIdx.x;
    if (t < e) {
        int d = dst[t];
        int pos = atomicAdd(&cursor[d], 1);
        csr[pos] = src[t];
    }
}

// ---------------- GEMM: C[M,Ncol] = A[M,K] @ B[K,Ncol], fp32 ----------------
// BM=BN=64, BK=32, 256 threads, 4x4 microtile per thread.

__global__ __launch_bounds__(256) void k_gemm(const float* __restrict__ A,
                                              const float* __restrict__ B,
                                              float* __restrict__ C,
                                              int M, int Ncol, int K) {
    __shared__ float As[64][33];  // [row][k], pad to break write conflicts
    __shared__ float Bs[32][65];  // [k][col]
    int t = threadIdx.x;
    int bm = blockIdx.x, bn = blockIdx.y;
    int ty = t >> 4, tx = t & 15;
    int row0 = bm * 64, col0 = bn * 64;
    float c[4][4] = {};
    for (int k0 = 0; k0 < K; k0 += 32) {
        #pragma unroll
        for (int j = 0; j < 8; ++j) {
            int idx = t + 256 * j;
            int r = idx >> 5, cc = idx & 31;
            int gr = row0 + r;
            As[r][cc] = (gr < M) ? A[(size_t)gr * K + k0 + cc] : 0.f;
        }
        #pragma unroll
        for (int j = 0; j < 8; ++j) {
            int idx = t + 256 * j;
            int r = idx >> 6, cc = idx & 63;
            int gc = col0 + cc;
            Bs[r][cc] = (gc < Ncol) ? B[(size_t)(k0 + r) * Ncol + gc] : 0.f;
        }
        __syncthreads();
        #pragma unroll
        for (int kk = 0; kk < 32; ++kk) {
            float a[4], b[4];
            #pragma unroll
            for (int i = 0; i < 4; ++i) a[i] = As[ty * 4 + i][kk];
            #pragma unroll
            for (int j = 0; j < 4; ++j) b[j] = Bs[kk][tx * 4 + j];
            #pragma unroll
            for (int i = 0; i < 4; ++i)
                #pragma unroll
                for (int j = 0; j < 4; ++j) c[i][j] += a[i] * b[j];
        }
        __syncthreads();
    }
    #pragma unroll
    for (int i = 0; i < 4; ++i) {
        int gr = row0 + ty * 4 + i;
        if (gr < M) {
            #pragma unroll
            for (int j = 0; j < 4; ++j) {
                int gc = col0 + tx * 4 + j;
                if (gc < Ncol) C[(size_t)gr * Ncol + gc] = c[i][j];
            }
        }
    }
}

static inline void gemm(const float* A, const float* B, float* C,
                        int M, int Ncol, int K, hipStream_t st) {
    dim3 g((M + 63) / 64, (Ncol + 63) / 64);
    k_gemm<<<g, 256, 0, st>>>(A, B, C, M, Ncol, K);
}

// ---------------- attention scores: el/er [N,H] ----------------

template <int H, int D>
__global__ __launch_bounds__(256) void k_attn(const float* __restrict__ feat,
                                              const float* __restrict__ al,
                                              const float* __restrict__ ar,
                                              float* __restrict__ el,
                                              float* __restrict__ er, int n) {
    int gw = blockIdx.x * 4 + (threadIdx.x >> 6);
    int lane = threadIdx.x & 63;
    int i = gw / H, h = gw % H;
    if (i >= n) return;
    float f = (lane < D) ? feat[i * (H * D) + h * D + lane] : 0.f;
    float wl = (lane < D) ? al[h * D + lane] : 0.f;
    float wr = (lane < D) ? ar[h * D + lane] : 0.f;
    float pl = f * wl, pr = f * wr;
    #pragma unroll
    for (int off = 32; off; off >>= 1) {
        pl += __shfl_xor(pl, off);
        pr += __shfl_xor(pr, off);
    }
    if (lane == 0) {
        el[i * H + h] = pl;
        er[i * H + h] = pr;
    }
}

// ---------------- edge-softmax aggregation ----------------
// One wave per (dst node, head); lane = feature channel.
// Pass 1: segment max in registers (lanes split edges, shfl reduce).
// Pass 2: den += exp(e-m); acc[d] += exp(e-m)*feat[src,d]. Normalize at end.
// ACT: 0 = none, 1 = elu

template <int H, int D, int ACT>
__global__ __launch_bounds__(256) void k_agg(const int* __restrict__ rowptr,
                                             const int* __restrict__ csr,
                                             const float* __restrict__ el,
                                             const float* __restrict__ er,
                                             const float* __restrict__ feat,
                                             float* __restrict__ out, int n) {
    int gw = blockIdx.x * 4 + (threadIdx.x >> 6);
    int lane = threadIdx.x & 63;
    int i = gw / H, h = gw % H;
    if (i >= n) return;
    int s0 = rowptr[i], s1 = rowptr[i + 1];
    float eri = er[i * H + h];

    float m = -INFINITY;
    for (int e = s0 + lane; e < s1; e += 64) {
        int s = csr[e];
        float v = el[s * H + h] + eri;
        v = v > 0.f ? v : 0.2f * v;
        m = fmaxf(m, v);
    }
    #pragma unroll
    for (int off = 32; off; off >>= 1) m = fmaxf(m, __shfl_xor(m, off));

    float den = 0.f, acc = 0.f;
    for (int e = s0; e < s1; ++e) {
        int s = csr[e];
        float v = el[s * H + h] + eri;
        v = v > 0.f ? v : 0.2f * v;
        float ex = __expf(v - m);
        den += ex;
        if (lane < D) acc += ex * feat[s * (H * D) + h * D + lane];
    }
    float o = (s1 > s0) ? acc / fmaxf(den, 1e-9f) : 0.f;
    if (ACT == 1) o = o > 0.f ? o : (__expf(o) - 1.f);
    if (lane < D) out[i * (H * D) + h * D + lane] = o;
}

// ---------------- launch ----------------

extern "C" void kernel_launch(void* const* d_in, const int* in_sizes, int n_in,
                              void* d_out, int out_size, void* d_ws, size_t ws_size,
                              hipStream_t stream) {
    const float* x    = (const float*)d_in[0];
    const int*   src  = (const int*)d_in[1];
    const int*   dst  = (const int*)d_in[2];
    const float* W00  = (const float*)d_in[3];
    const float* a00l = (const float*)d_in[4];
    const float* a00r = (const float*)d_in[5];
    const float* W01  = (const float*)d_in[6];
    const float* a01l = (const float*)d_in[7];
    const float* a01r = (const float*)d_in[8];
    const float* W0f  = (const float*)d_in[9];
    const float* a0fl = (const float*)d_in[10];
    const float* a0fr = (const float*)d_in[11];
    const float* W10  = (const float*)d_in[12];
    const float* a10l = (const float*)d_in[13];
    const float* a10r = (const float*)d_in[14];
    const float* W1f  = (const float*)d_in[15];
    const float* a1fl = (const float*)d_in[16];
    const float* a1fr = (const float*)d_in[17];
    const float* W1o  = (const float*)d_in[18];
    const float* a1ol = (const float*)d_in[19];
    const float* a1or = (const float*)d_in[20];
    float* out = (float*)d_out;

    const int n = in_sizes[0] / 256;  // 50000
    const int e = in_sizes[1];        // 800000
    const int C = 40;

    // workspace carve-up (256B aligned)
    char* p = (char*)d_ws;
    auto alloc = [&](size_t bytes) -> void* {
        void* r = (void*)p;
        p += (bytes + 255) & ~(size_t)255;
        return r;
    };
    int*   deg    = (int*)alloc((size_t)n * 4);
    int*   tmp    = (int*)alloc((size_t)n * 4);
    int*   bsum   = (int*)alloc(64 * 4);
    int*   rowptr = (int*)alloc((size_t)(n + 1) * 4);
    int*   cursor = (int*)alloc((size_t)n * 4);
    int*   csr    = (int*)alloc((size_t)e * 4);
    float* el     = (float*)alloc((size_t)n * 4 * 4);
    float* er     = (float*)alloc((size_t)n * 4 * 4);
    float* feat   = (float*)alloc((size_t)n * 256 * 4);
    float* hbuf   = (float*)alloc((size_t)n * 256 * 4);

    // ---- CSR build (graph shared by all 6 convs) ----
    hipMemsetAsync(deg, 0, (size_t)n * 4, stream);
    k_hist<<<(e + 255) / 256, 256, 0, stream>>>(dst, deg, e);
    int nb = (n + 1023) / 1024;
    k_scan1<<<nb, 1024, 0, stream>>>(deg, tmp, bsum, n);
    k_scan2<<<1, 1, 0, stream>>>(bsum, nb);
    k_scan3<<<(n + 255) / 256, 256, 0, stream>>>(deg, tmp, bsum, rowptr, cursor, n);
    k_scatter<<<(e + 255) / 256, 256, 0, stream>>>(src, dst, cursor, csr, e);

    int gw4 = (n * 4 + 3) / 4;  // blocks for H=4 (4 waves/block)
    int gw1 = (n + 3) / 4;      // blocks for H=1

    // ---- branch 0 ----
    gemm(x, W00, feat, n, 256, 256, stream);
    k_attn<4, 64><<<gw4, 256, 0, stream>>>(feat, a00l, a00r, el, er, n);
    k_agg<4, 64, 1><<<gw4, 256, 0, stream>>>(rowptr, csr, el, er, feat, hbuf, n);

    gemm(hbuf, W01, feat, n, 64, 256, stream);
    k_attn<1, 64><<<gw1, 256, 0, stream>>>(feat, a01l, a01r, el, er, n);
    k_agg<1, 64, 1><<<gw1, 256, 0, stream>>>(rowptr, csr, el, er, feat, hbuf, n);

    gemm(hbuf, W0f, feat, n, C, 64, stream);
    k_attn<1, 40><<<gw1, 256, 0, stream>>>(feat, a0fl, a0fr, el, er, n);
    k_agg<1, 40, 0><<<gw1, 256, 0, stream>>>(rowptr, csr, el, er, feat, out, n);

    // ---- branch 1 ----
    gemm(x, W10, feat, n, 256, 256, stream);
    k_attn<4, 64><<<gw4, 256, 0, stream>>>(feat, a10l, a10r, el, er, n);
    k_agg<4, 64, 1><<<gw4, 256, 0, stream>>>(rowptr, csr, el, er, feat, hbuf, n);

    gemm(hbuf, W1f, feat, n, 64, 256, stream);
    k_attn<1, 64><<<gw1, 256, 0, stream>>>(feat, a1fl, a1fr, el, er, n);
    k_agg<1, 64, 0><<<gw1, 256, 0, stream>>>(rowptr, csr, el, er, feat, hbuf, n);

    gemm(hbuf, W1o, feat, n, C, 64, stream);
    k_attn<1, 40><<<gw1, 256, 0, stream>>>(feat, a1ol, a1or, el, er, n);
    k_agg<1, 40, 1><<<gw1, 256, 0, stream>>>(rowptr, csr, el, er, feat, out + (size_t)n * C, n);
}

// Round 3
// 1343.040 us; speedup vs baseline: 1.4353x; 1.4353x over previous
//
#include <hip/hip_runtime.h>
#include <math.h>

// ---------------- CSR build ----------------

__global__ void k_hist(const int* __restrict__ dst, int* __restrict__ deg, int e) {
    int t = blockIdx.x * 256 + threadIdx.x;
    if (t < e) atomicAdd(&deg[dst[t]], 1);
}

__global__ void k_scan1(const int* __restrict__ deg, int* __restrict__ tmp,
                        int* __restrict__ bsum, int n) {
    __shared__ int s[1024];
    int t = threadIdx.x;
    int g = blockIdx.x * 1024 + t;
    int v = (g < n) ? deg[g] : 0;
    s[t] = v;
    __syncthreads();
    for (int off = 1; off < 1024; off <<= 1) {
        int u = (t >= off) ? s[t - off] : 0;
        __syncthreads();
        s[t] += u;
        __syncthreads();
    }
    if (g < n) tmp[g] = s[t];
    if (t == 1023) bsum[blockIdx.x] = s[t];
}

__global__ void k_scan2(int* bsum, int nb) {
    int acc = 0;
    for (int b = 0; b < nb; ++b) { int v = bsum[b]; bsum[b] = acc; acc += v; }
}

__global__ void k_scan3(const int* __restrict__ deg, const int* __restrict__ tmp,
                        const int* __restrict__ bsum, int* __restrict__ rowptr,
                        int* __restrict__ cursor, int n) {
    int g = blockIdx.x * 256 + threadIdx.x;
    if (g < n) {
        int incl = tmp[g] + bsum[g >> 10];
        rowptr[g + 1] = incl;
        cursor[g] = incl - deg[g];
        if (g == 0) rowptr[0] = 0;
    }
}

__global__ void k_scatter(const int* __restrict__ src, const int* __restrict__ dst,
                          int* __restrict__ cursor, int* __restrict__ csr, int e) {
    int t = blockIdx.x * 256 + threadIdx.x;
    if (t < e) {
        int d = dst[t];
        int pos = atomicAdd(&cursor[d], 1);
        csr[pos] = src[t];
    }
}

// ---------------- GEMM: C[M,Ncol] = A[M,K] @ B[K,Ncol], fp32 ----------------

__global__ __launch_bounds__(256) void k_gemm(const float* __restrict__ A,
                                              const float* __restrict__ B,
                                              float* __restrict__ C,
                                              int M, int Ncol, int K) {
    __shared__ float As[64][33];
    __shared__ float Bs[32][65];
    int t = threadIdx.x;
    int bm = blockIdx.x, bn = blockIdx.y;
    int ty = t >> 4, tx = t & 15;
    int row0 = bm * 64, col0 = bn * 64;
    float c[4][4] = {};
    for (int k0 = 0; k0 < K; k0 += 32) {
        #pragma unroll
        for (int j = 0; j < 8; ++j) {
            int idx = t + 256 * j;
            int r = idx >> 5, cc = idx & 31;
            int gr = row0 + r;
            As[r][cc] = (gr < M) ? A[(size_t)gr * K + k0 + cc] : 0.f;
        }
        #pragma unroll
        for (int j = 0; j < 8; ++j) {
            int idx = t + 256 * j;
            int r = idx >> 6, cc = idx & 63;
            int gc = col0 + cc;
            Bs[r][cc] = (gc < Ncol) ? B[(size_t)(k0 + r) * Ncol + gc] : 0.f;
        }
        __syncthreads();
        #pragma unroll
        for (int kk = 0; kk < 32; ++kk) {
            float a[4], b[4];
            #pragma unroll
            for (int i = 0; i < 4; ++i) a[i] = As[ty * 4 + i][kk];
            #pragma unroll
            for (int j = 0; j < 4; ++j) b[j] = Bs[kk][tx * 4 + j];
            #pragma unroll
            for (int i = 0; i < 4; ++i)
                #pragma unroll
                for (int j = 0; j < 4; ++j) c[i][j] += a[i] * b[j];
        }
        __syncthreads();
    }
    #pragma unroll
    for (int i = 0; i < 4; ++i) {
        int gr = row0 + ty * 4 + i;
        if (gr < M) {
            #pragma unroll
            for (int j = 0; j < 4; ++j) {
                int gc = col0 + tx * 4 + j;
                if (gc < Ncol) C[(size_t)gr * Ncol + gc] = c[i][j];
            }
        }
    }
}

static inline void gemm(const float* A, const float* B, float* C,
                        int M, int Ncol, int K, hipStream_t st) {
    dim3 g((M + 63) / 64, (Ncol + 63) / 64);
    k_gemm<<<g, 256, 0, st>>>(A, B, C, M, Ncol, K);
}

// ---------------- attention scores: el/er [N,H] ----------------

template <int H, int D>
__global__ __launch_bounds__(256) void k_attn(const float* __restrict__ feat,
                                              const float* __restrict__ al,
                                              const float* __restrict__ ar,
                                              float* __restrict__ el,
                                              float* __restrict__ er, int n) {
    int gw = blockIdx.x * 4 + (threadIdx.x >> 6);
    int lane = threadIdx.x & 63;
    int i = gw / H, h = gw % H;
    if (i >= n) return;
    float f = (lane < D) ? feat[i * (H * D) + h * D + lane] : 0.f;
    float wl = (lane < D) ? al[h * D + lane] : 0.f;
    float wr = (lane < D) ? ar[h * D + lane] : 0.f;
    float pl = f * wl, pr = f * wr;
    #pragma unroll
    for (int off = 32; off; off >>= 1) {
        pl += __shfl_xor(pl, off);
        pr += __shfl_xor(pr, off);
    }
    if (lane == 0) {
        el[i * H + h] = pl;
        er[i * H + h] = pr;
    }
}

// ---------------- edge-softmax aggregation ----------------

__device__ __forceinline__ float lrelu(float v) { return v > 0.f ? v : 0.2f * v; }

// H=4, D=64: one BLOCK per dst node. 256 threads = 4 heads x 64 channels.
// csr/el reads amortized across heads; feat read is one coalesced 1KB/edge.
// Pass 2 unrolled x4 for memory-level parallelism.
template <int ACT>
__global__ __launch_bounds__(256) void k_agg4(const int* __restrict__ rowptr,
                                              const int* __restrict__ csr,
                                              const float* __restrict__ el,
                                              const float* __restrict__ er,
                                              const float* __restrict__ feat,
                                              float* __restrict__ out, int n) {
    int i = blockIdx.x;
    int t = threadIdx.x;
    int h = t >> 6;
    int lane = t & 63;
    int s0 = rowptr[i], s1 = rowptr[i + 1];
    float eri = er[i * 4 + h];

    // pass 1: per-head row max (lanes split edges; wave reduce)
    float m = -INFINITY;
    for (int e = s0 + lane; e < s1; e += 64)
        m = fmaxf(m, lrelu(el[csr[e] * 4 + h] + eri));
    #pragma unroll
    for (int off = 32; off; off >>= 1) m = fmaxf(m, __shfl_xor(m, off));

    // pass 2: unrolled x4
    float den = 0.f, acc = 0.f;
    int e = s0;
    for (; e + 4 <= s1; e += 4) {
        int sa = csr[e], sb = csr[e + 1], sc = csr[e + 2], sd = csr[e + 3];
        float va = lrelu(el[sa * 4 + h] + eri);
        float vb = lrelu(el[sb * 4 + h] + eri);
        float vc = lrelu(el[sc * 4 + h] + eri);
        float vd = lrelu(el[sd * 4 + h] + eri);
        float fa = feat[(size_t)sa * 256 + t];
        float fb = feat[(size_t)sb * 256 + t];
        float fc = feat[(size_t)sc * 256 + t];
        float fd = feat[(size_t)sd * 256 + t];
        float xa = __expf(va - m), xb = __expf(vb - m);
        float xc = __expf(vc - m), xd = __expf(vd - m);
        den += (xa + xb) + (xc + xd);
        acc = fmaf(xa, fa, fmaf(xb, fb, fmaf(xc, fc, fmaf(xd, fd, acc))));
    }
    for (; e < s1; ++e) {
        int s = csr[e];
        float v = lrelu(el[s * 4 + h] + eri);
        float ex = __expf(v - m);
        den += ex;
        acc = fmaf(ex, feat[(size_t)s * 256 + t], acc);
    }
    float o = (s1 > s0) ? acc / fmaxf(den, 1e-9f) : 0.f;
    if (ACT == 1) o = o > 0.f ? o : (__expf(o) - 1.f);
    out[(size_t)i * 256 + t] = o;
}

// H=1: one WAVE per dst node (4 waves/block), unrolled x4.
template <int D, int ACT>
__global__ __launch_bounds__(256) void k_agg1(const int* __restrict__ rowptr,
                                              const int* __restrict__ csr,
                                              const float* __restrict__ el,
                                              const float* __restrict__ er,
                                              const float* __restrict__ feat,
                                              float* __restrict__ out, int n) {
    int i = blockIdx.x * 4 + (threadIdx.x >> 6);
    int lane = threadIdx.x & 63;
    if (i >= n) return;
    int s0 = rowptr[i], s1 = rowptr[i + 1];
    float eri = er[i];

    float m = -INFINITY;
    for (int e = s0 + lane; e < s1; e += 64)
        m = fmaxf(m, lrelu(el[csr[e]] + eri));
    #pragma unroll
    for (int off = 32; off; off >>= 1) m = fmaxf(m, __shfl_xor(m, off));

    float den = 0.f, acc = 0.f;
    bool act = lane < D;
    int e = s0;
    for (; e + 4 <= s1; e += 4) {
        int sa = csr[e], sb = csr[e + 1], sc = csr[e + 2], sd = csr[e + 3];
        float va = lrelu(el[sa] + eri);
        float vb = lrelu(el[sb] + eri);
        float vc = lrelu(el[sc] + eri);
        float vd = lrelu(el[sd] + eri);
        float fa = act ? feat[(size_t)sa * D + lane] : 0.f;
        float fb = act ? feat[(size_t)sb * D + lane] : 0.f;
        float fc = act ? feat[(size_t)sc * D + lane] : 0.f;
        float fd = act ? feat[(size_t)sd * D + lane] : 0.f;
        float xa = __expf(va - m), xb = __expf(vb - m);
        float xc = __expf(vc - m), xd = __expf(vd - m);
        den += (xa + xb) + (xc + xd);
        acc = fmaf(xa, fa, fmaf(xb, fb, fmaf(xc, fc, fmaf(xd, fd, acc))));
    }
    for (; e < s1; ++e) {
        int s = csr[e];
        float v = lrelu(el[s] + eri);
        float ex = __expf(v - m);
        den += ex;
        acc = fmaf(ex, act ? feat[(size_t)s * D + lane] : 0.f, acc);
    }
    float o = (s1 > s0) ? acc / fmaxf(den, 1e-9f) : 0.f;
    if (ACT == 1) o = o > 0.f ? o : (__expf(o) - 1.f);
    if (act) out[(size_t)i * D + lane] = o;
}

// ---------------- launch ----------------

extern "C" void kernel_launch(void* const* d_in, const int* in_sizes, int n_in,
                              void* d_out, int out_size, void* d_ws, size_t ws_size,
                              hipStream_t stream) {
    const float* x    = (const float*)d_in[0];
    const int*   src  = (const int*)d_in[1];
    const int*   dst  = (const int*)d_in[2];
    const float* W00  = (const float*)d_in[3];
    const float* a00l = (const float*)d_in[4];
    const float* a00r = (const float*)d_in[5];
    const float* W01  = (const float*)d_in[6];
    const float* a01l = (const float*)d_in[7];
    const float* a01r = (const float*)d_in[8];
    const float* W0f  = (const float*)d_in[9];
    const float* a0fl = (const float*)d_in[10];
    const float* a0fr = (const float*)d_in[11];
    const float* W10  = (const float*)d_in[12];
    const float* a10l = (const float*)d_in[13];
    const float* a10r = (const float*)d_in[14];
    const float* W1f  = (const float*)d_in[15];
    const float* a1fl = (const float*)d_in[16];
    const float* a1fr = (const float*)d_in[17];
    const float* W1o  = (const float*)d_in[18];
    const float* a1ol = (const float*)d_in[19];
    const float* a1or = (const float*)d_in[20];
    float* out = (float*)d_out;

    const int n = in_sizes[0] / 256;  // 50000
    const int e = in_sizes[1];        // 800000
    const int C = 40;

    char* p = (char*)d_ws;
    auto alloc = [&](size_t bytes) -> void* {
        void* r = (void*)p;
        p += (bytes + 255) & ~(size_t)255;
        return r;
    };
    int*   deg    = (int*)alloc((size_t)n * 4);
    int*   tmp    = (int*)alloc((size_t)n * 4);
    int*   bsum   = (int*)alloc(64 * 4);
    int*   rowptr = (int*)alloc((size_t)(n + 1) * 4);
    int*   cursor = (int*)alloc((size_t)n * 4);
    int*   csr    = (int*)alloc((size_t)e * 4);
    float* el     = (float*)alloc((size_t)n * 4 * 4);
    float* er     = (float*)alloc((size_t)n * 4 * 4);
    float* feat   = (float*)alloc((size_t)n * 256 * 4);
    float* hbuf   = (float*)alloc((size_t)n * 256 * 4);

    // ---- CSR build ----
    hipMemsetAsync(deg, 0, (size_t)n * 4, stream);
    k_hist<<<(e + 255) / 256, 256, 0, stream>>>(dst, deg, e);
    int nb = (n + 1023) / 1024;
    k_scan1<<<nb, 1024, 0, stream>>>(deg, tmp, bsum, n);
    k_scan2<<<1, 1, 0, stream>>>(bsum, nb);
    k_scan3<<<(n + 255) / 256, 256, 0, stream>>>(deg, tmp, bsum, rowptr, cursor, n);
    k_scatter<<<(e + 255) / 256, 256, 0, stream>>>(src, dst, cursor, csr, e);

    int gw4 = (n * 4 + 3) / 4;
    int gw1 = (n + 3) / 4;

    // ---- branch 0 ----
    gemm(x, W00, feat, n, 256, 256, stream);
    k_attn<4, 64><<<gw4, 256, 0, stream>>>(feat, a00l, a00r, el, er, n);
    k_agg4<1><<<n, 256, 0, stream>>>(rowptr, csr, el, er, feat, hbuf, n);

    gemm(hbuf, W01, feat, n, 64, 256, stream);
    k_attn<1, 64><<<gw1, 256, 0, stream>>>(feat, a01l, a01r, el, er, n);
    k_agg1<64, 1><<<gw1, 256, 0, stream>>>(rowptr, csr, el, er, feat, hbuf, n);

    gemm(hbuf, W0f, feat, n, C, 64, stream);
    k_attn<1, 40><<<gw1, 256, 0, stream>>>(feat, a0fl, a0fr, el, er, n);
    k_agg1<40, 0><<<gw1, 256, 0, stream>>>(rowptr, csr, el, er, feat, out, n);

    // ---- branch 1 ----
    gemm(x, W10, feat, n, 256, 256, stream);
    k_attn<4, 64><<<gw4, 256, 0, stream>>>(feat, a10l, a10r, el, er, n);
    k_agg4<1><<<n, 256, 0, stream>>>(rowptr, csr, el, er, feat, hbuf, n);

    gemm(hbuf, W1f, feat, n, 64, 256, stream);
    k_attn<1, 64><<<gw1, 256, 0, stream>>>(feat, a1fl, a1fr, el, er, n);
    k_agg1<64, 0><<<gw1, 256, 0, stream>>>(rowptr, csr, el, er, feat, hbuf, n);

    gemm(hbuf, W1o, feat, n, C, 64, stream);
    k_attn<1, 40><<<gw1, 256, 0, stream>>>(feat, a1ol, a1or, el, er, n);
    k_agg1<40, 1><<<gw1, 256, 0, stream>>>(rowptr, csr, el, er, feat, out + (size_t)n * C, n);
}

// Round 5
// 918.526 us; speedup vs baseline: 2.0986x; 1.4622x over previous
//
#include <hip/hip_runtime.h>
#include <math.h>

typedef __attribute__((ext_vector_type(8))) short bf16x8;
typedef __attribute__((ext_vector_type(4))) float f32x4;

__device__ __forceinline__ unsigned short f2bf(float f) {
    unsigned int u = __float_as_uint(f);
    unsigned int r = (u + 0x7FFF + ((u >> 16) & 1)) >> 16;  // RNE
    return (unsigned short)r;
}
__device__ __forceinline__ float bf2f(unsigned short h) {
    return __uint_as_float((unsigned int)h << 16);
}
// split x into hi+lo bf16 (captures ~16 mantissa bits)
__device__ __forceinline__ void split_bf(float x, unsigned short& hi, unsigned short& lo) {
    hi = f2bf(x);
    lo = f2bf(x - bf2f(hi));
}

// ---------------- CSR build ----------------

__global__ void k_hist(const int* __restrict__ dst, int* __restrict__ deg, int e) {
    int t = blockIdx.x * 256 + threadIdx.x;
    if (t < e) atomicAdd(&deg[dst[t]], 1);
}

__global__ void k_scan1(const int* __restrict__ deg, int* __restrict__ tmp,
                        int* __restrict__ bsum, int n) {
    __shared__ int s[1024];
    int t = threadIdx.x;
    int g = blockIdx.x * 1024 + t;
    int v = (g < n) ? deg[g] : 0;
    s[t] = v;
    __syncthreads();
    for (int off = 1; off < 1024; off <<= 1) {
        int u = (t >= off) ? s[t - off] : 0;
        __syncthreads();
        s[t] += u;
        __syncthreads();
    }
    if (g < n) tmp[g] = s[t];
    if (t == 1023) bsum[blockIdx.x] = s[t];
}

__global__ void k_scan2(int* bsum, int nb) {
    int acc = 0;
    for (int b = 0; b < nb; ++b) { int v = bsum[b]; bsum[b] = acc; acc += v; }
}

__global__ void k_scan3(const int* __restrict__ deg, const int* __restrict__ tmp,
                        const int* __restrict__ bsum, int* __restrict__ rowptr,
                        int* __restrict__ cursor, int n) {
    int g = blockIdx.x * 256 + threadIdx.x;
    if (g < n) {
        int incl = tmp[g] + bsum[g >> 10];
        rowptr[g + 1] = incl;
        cursor[g] = incl - deg[g];
        if (g == 0) rowptr[0] = 0;
    }
}

__global__ void k_scatter(const int* __restrict__ src, const int* __restrict__ dst,
                          int* __restrict__ cursor, int* __restrict__ csr, int e) {
    int t = blockIdx.x * 256 + threadIdx.x;
    if (t < e) {
        int d = dst[t];
        int pos = atomicAdd(&cursor[d], 1);
        csr[pos] = src[t];
    }
}

// ---------------- casts (split hi/lo) ----------------

__global__ void k_castx(const float* __restrict__ x, unsigned short* __restrict__ xhi,
                        unsigned short* __restrict__ xlo, int nelem) {
    int t = blockIdx.x * 256 + threadIdx.x;
    if (t < nelem) {
        unsigned short h, l;
        split_bf(x[t], h, l);
        xhi[t] = h; xlo[t] = l;
    }
}

// W [K][N] fp32 -> Wt [N][K] bf16 hi/lo
__global__ void k_castw(const float* __restrict__ W, unsigned short* __restrict__ Whi,
                        unsigned short* __restrict__ Wlo, int K, int N) {
    int t = blockIdx.x * 256 + threadIdx.x;
    if (t < K * N) {
        int k = t / N, n = t - k * N;
        unsigned short h, l;
        split_bf(W[t], h, l);
        Whi[n * K + k] = h; Wlo[n * K + k] = l;
    }
}

// ------- split-bf16 MFMA GEMM (NT): C = A @ Bt^T, ~fp32 accuracy ----------
// acc += ahi*bhi + alo*bhi + ahi*blo  (drop lo*lo, ~2^-18 rel)
// Block 256 thr = 4 waves, tile 64x64, BK=32. Wave w -> cols [w*16, w*16+16).
// Fragment layout (verified m89/m91): A/B idx=lane&15, k=(lane>>4)*8+j;
// D col=lane&15, row=(lane>>4)*4+reg. LDS rows padded to 40 bf16.

#define LDP 40

__global__ __launch_bounds__(256) void k_gemm_split(const unsigned short* __restrict__ Ahi,
                                                    const unsigned short* __restrict__ Alo,
                                                    const unsigned short* __restrict__ Bhi,
                                                    const unsigned short* __restrict__ Blo,
                                                    float* __restrict__ C,
                                                    int M, int Ncol, int K) {
    __shared__ unsigned short Ash[64 * LDP];
    __shared__ unsigned short Asl[64 * LDP];
    __shared__ unsigned short Bsh[64 * LDP];
    __shared__ unsigned short Bsl[64 * LDP];
    int t = threadIdx.x;
    int w = t >> 6, lane = t & 63;
    int lrow = lane & 15, kgrp = (lane >> 4) * 8;
    int row0 = blockIdx.x * 64, col0 = blockIdx.y * 64;
    int trow = t >> 2, tcol = (t & 3) * 8;

    f32x4 acc[4] = {{0.f, 0.f, 0.f, 0.f}, {0.f, 0.f, 0.f, 0.f},
                    {0.f, 0.f, 0.f, 0.f}, {0.f, 0.f, 0.f, 0.f}};

    for (int k0 = 0; k0 < K; k0 += 32) {
        uint4 ah = {0u,0u,0u,0u}, al = {0u,0u,0u,0u};
        uint4 bh = {0u,0u,0u,0u}, bl = {0u,0u,0u,0u};
        int gr = row0 + trow;
        if (gr < M) {
            ah = *(const uint4*)(Ahi + (size_t)gr * K + k0 + tcol);
            al = *(const uint4*)(Alo + (size_t)gr * K + k0 + tcol);
        }
        int gc = col0 + trow;
        if (gc < Ncol) {
            bh = *(const uint4*)(Bhi + (size_t)gc * K + k0 + tcol);
            bl = *(const uint4*)(Blo + (size_t)gc * K + k0 + tcol);
        }
        __syncthreads();
        *(uint4*)&Ash[trow * LDP + tcol] = ah;
        *(uint4*)&Asl[trow * LDP + tcol] = al;
        *(uint4*)&Bsh[trow * LDP + tcol] = bh;
        *(uint4*)&Bsl[trow * LDP + tcol] = bl;
        __syncthreads();
        bf16x8 vbh = *(const bf16x8*)&Bsh[(w * 16 + lrow) * LDP + kgrp];
        bf16x8 vbl = *(const bf16x8*)&Bsl[(w * 16 + lrow) * LDP + kgrp];
        #pragma unroll
        for (int mt = 0; mt < 4; ++mt) {
            bf16x8 vah = *(const bf16x8*)&Ash[(mt * 16 + lrow) * LDP + kgrp];
            bf16x8 val = *(const bf16x8*)&Asl[(mt * 16 + lrow) * LDP + kgrp];
            acc[mt] = __builtin_amdgcn_mfma_f32_16x16x32_bf16(vah, vbh, acc[mt], 0, 0, 0);
            acc[mt] = __builtin_amdgcn_mfma_f32_16x16x32_bf16(val, vbh, acc[mt], 0, 0, 0);
            acc[mt] = __builtin_amdgcn_mfma_f32_16x16x32_bf16(vah, vbl, acc[mt], 0, 0, 0);
        }
    }

    int ocol = col0 + w * 16 + lrow;
    if (ocol < Ncol) {
        int orow = (lane >> 4) * 4;
        #pragma unroll
        for (int mt = 0; mt < 4; ++mt) {
            #pragma unroll
            for (int r = 0; r < 4; ++r) {
                int m = row0 + mt * 16 + orow + r;
                if (m < M) C[(size_t)m * Ncol + ocol] = acc[mt][r];
            }
        }
    }
}

static inline void gemm_split(const unsigned short* Ah, const unsigned short* Al,
                              const unsigned short* Bh, const unsigned short* Bl,
                              float* C, int M, int Ncol, int K, hipStream_t st) {
    dim3 g((M + 63) / 64, (Ncol + 63) / 64);
    k_gemm_split<<<g, 256, 0, st>>>(Ah, Al, Bh, Bl, C, M, Ncol, K);
}

// ---------------- attention scores: el/er [N,H] ----------------

template <int H, int D>
__global__ __launch_bounds__(256) void k_attn(const float* __restrict__ feat,
                                              const float* __restrict__ al,
                                              const float* __restrict__ ar,
                                              float* __restrict__ el,
                                              float* __restrict__ er, int n) {
    int gw = blockIdx.x * 4 + (threadIdx.x >> 6);
    int lane = threadIdx.x & 63;
    int i = gw / H, h = gw % H;
    if (i >= n) return;
    float f = (lane < D) ? feat[i * (H * D) + h * D + lane] : 0.f;
    float wl = (lane < D) ? al[h * D + lane] : 0.f;
    float wr = (lane < D) ? ar[h * D + lane] : 0.f;
    float pl = f * wl, pr = f * wr;
    #pragma unroll
    for (int off = 32; off; off >>= 1) {
        pl += __shfl_xor(pl, off);
        pr += __shfl_xor(pr, off);
    }
    if (lane == 0) {
        el[i * H + h] = pl;
        er[i * H + h] = pr;
    }
}

// ---------------- edge-softmax aggregation ----------------

__device__ __forceinline__ float lrelu(float v) { return v > 0.f ? v : 0.2f * v; }

// H=4, D=64: one BLOCK per dst node; 256 thr = 4 heads x 64 ch.
// SPLITOUT: write bf16 hi/lo pair (feeds split GEMM) vs fp32 out.
template <int ACT, int SPLITOUT>
__global__ __launch_bounds__(256) void k_agg4(const int* __restrict__ rowptr,
                                              const int* __restrict__ csr,
                                              const float* __restrict__ el,
                                              const float* __restrict__ er,
                                              const float* __restrict__ feat,
                                              unsigned short* __restrict__ ohi,
                                              unsigned short* __restrict__ olo,
                                              float* __restrict__ ofp, int n) {
    int i = blockIdx.x;
    int t = threadIdx.x;
    int h = t >> 6;
    int lane = t & 63;
    int s0 = rowptr[i], s1 = rowptr[i + 1];
    float eri = er[i * 4 + h];

    float m = -INFINITY;
    for (int e = s0 + lane; e < s1; e += 64)
        m = fmaxf(m, lrelu(el[csr[e] * 4 + h] + eri));
    #pragma unroll
    for (int off = 32; off; off >>= 1) m = fmaxf(m, __shfl_xor(m, off));

    float den = 0.f, acc = 0.f;
    int e = s0;
    for (; e + 4 <= s1; e += 4) {
        int sa = csr[e], sb = csr[e + 1], sc = csr[e + 2], sd = csr[e + 3];
        float va = lrelu(el[sa * 4 + h] + eri);
        float vb = lrelu(el[sb * 4 + h] + eri);
        float vc = lrelu(el[sc * 4 + h] + eri);
        float vd = lrelu(el[sd * 4 + h] + eri);
        float fa = feat[(size_t)sa * 256 + t];
        float fb = feat[(size_t)sb * 256 + t];
        float fc = feat[(size_t)sc * 256 + t];
        float fd = feat[(size_t)sd * 256 + t];
        float xa = __expf(va - m), xb = __expf(vb - m);
        float xc = __expf(vc - m), xd = __expf(vd - m);
        den += (xa + xb) + (xc + xd);
        acc = fmaf(xa, fa, fmaf(xb, fb, fmaf(xc, fc, fmaf(xd, fd, acc))));
    }
    for (; e < s1; ++e) {
        int s = csr[e];
        float v = lrelu(el[s * 4 + h] + eri);
        float ex = __expf(v - m);
        den += ex;
        acc = fmaf(ex, feat[(size_t)s * 256 + t], acc);
    }
    float o = (s1 > s0) ? acc / fmaxf(den, 1e-9f) : 0.f;
    if (ACT == 1) o = o > 0.f ? o : (__expf(o) - 1.f);
    if (SPLITOUT) {
        unsigned short hh, ll;
        split_bf(o, hh, ll);
        ohi[(size_t)i * 256 + t] = hh;
        olo[(size_t)i * 256 + t] = ll;
    } else {
        ofp[(size_t)i * 256 + t] = o;
    }
}

// H=1: one WAVE per dst node (4 waves/block).
template <int D, int ACT, int SPLITOUT>
__global__ __launch_bounds__(256) void k_agg1(const int* __restrict__ rowptr,
                                              const int* __restrict__ csr,
                                              const float* __restrict__ el,
                                              const float* __restrict__ er,
                                              const float* __restrict__ feat,
                                              unsigned short* __restrict__ ohi,
                                              unsigned short* __restrict__ olo,
                                              float* __restrict__ ofp, int n) {
    int i = blockIdx.x * 4 + (threadIdx.x >> 6);
    int lane = threadIdx.x & 63;
    if (i >= n) return;
    int s0 = rowptr[i], s1 = rowptr[i + 1];
    float eri = er[i];

    float m = -INFINITY;
    for (int e = s0 + lane; e < s1; e += 64)
        m = fmaxf(m, lrelu(el[csr[e]] + eri));
    #pragma unroll
    for (int off = 32; off; off >>= 1) m = fmaxf(m, __shfl_xor(m, off));

    float den = 0.f, acc = 0.f;
    bool act = lane < D;
    int e = s0;
    for (; e + 4 <= s1; e += 4) {
        int sa = csr[e], sb = csr[e + 1], sc = csr[e + 2], sd = csr[e + 3];
        float va = lrelu(el[sa] + eri);
        float vb = lrelu(el[sb] + eri);
        float vc = lrelu(el[sc] + eri);
        float vd = lrelu(el[sd] + eri);
        float fa = act ? feat[(size_t)sa * D + lane] : 0.f;
        float fb = act ? feat[(size_t)sb * D + lane] : 0.f;
        float fc = act ? feat[(size_t)sc * D + lane] : 0.f;
        float fd = act ? feat[(size_t)sd * D + lane] : 0.f;
        float xa = __expf(va - m), xb = __expf(vb - m);
        float xc = __expf(vc - m), xd = __expf(vd - m);
        den += (xa + xb) + (xc + xd);
        acc = fmaf(xa, fa, fmaf(xb, fb, fmaf(xc, fc, fmaf(xd, fd, acc))));
    }
    for (; e < s1; ++e) {
        int s = csr[e];
        float v = lrelu(el[s] + eri);
        float ex = __expf(v - m);
        den += ex;
        acc = fmaf(ex, act ? feat[(size_t)s * D + lane] : 0.f, acc);
    }
    float o = (s1 > s0) ? acc / fmaxf(den, 1e-9f) : 0.f;
    if (ACT == 1) o = o > 0.f ? o : (__expf(o) - 1.f);
    if (act) {
        if (SPLITOUT) {
            unsigned short hh, ll;
            split_bf(o, hh, ll);
            ohi[(size_t)i * D + lane] = hh;
            olo[(size_t)i * D + lane] = ll;
        } else {
            ofp[(size_t)i * D + lane] = o;
        }
    }
}

// ---------------- launch ----------------

extern "C" void kernel_launch(void* const* d_in, const int* in_sizes, int n_in,
                              void* d_out, int out_size, void* d_ws, size_t ws_size,
                              hipStream_t stream) {
    const float* x    = (const float*)d_in[0];
    const int*   src  = (const int*)d_in[1];
    const int*   dst  = (const int*)d_in[2];
    const float* W00  = (const float*)d_in[3];
    const float* a00l = (const float*)d_in[4];
    const float* a00r = (const float*)d_in[5];
    const float* W01  = (const float*)d_in[6];
    const float* a01l = (const float*)d_in[7];
    const float* a01r = (const float*)d_in[8];
    const float* W0f  = (const float*)d_in[9];
    const float* a0fl = (const float*)d_in[10];
    const float* a0fr = (const float*)d_in[11];
    const float* W10  = (const float*)d_in[12];
    const float* a10l = (const float*)d_in[13];
    const float* a10r = (const float*)d_in[14];
    const float* W1f  = (const float*)d_in[15];
    const float* a1fl = (const float*)d_in[16];
    const float* a1fr = (const float*)d_in[17];
    const float* W1o  = (const float*)d_in[18];
    const float* a1ol = (const float*)d_in[19];
    const float* a1or = (const float*)d_in[20];
    float* out = (float*)d_out;

    const int n = in_sizes[0] / 256;  // 50000
    const int e = in_sizes[1];        // 800000
    const int C = 40;

    char* p = (char*)d_ws;
    auto alloc = [&](size_t bytes) -> void* {
        void* r = (void*)p;
        p += (bytes + 255) & ~(size_t)255;
        return r;
    };
    int*   deg    = (int*)alloc((size_t)n * 4);
    int*   tmp    = (int*)alloc((size_t)n * 4);
    int*   bsum   = (int*)alloc(64 * 4);
    int*   rowptr = (int*)alloc((size_t)(n + 1) * 4);
    int*   cursor = (int*)alloc((size_t)n * 4);
    int*   csr    = (int*)alloc((size_t)e * 4);
    float* el     = (float*)alloc((size_t)n * 4 * 4);
    float* er     = (float*)alloc((size_t)n * 4 * 4);
    float* feat   = (float*)alloc((size_t)n * 256 * 4);                  // fp32 GEMM out
    unsigned short* xhi = (unsigned short*)alloc((size_t)n * 256 * 2);
    unsigned short* xlo = (unsigned short*)alloc((size_t)n * 256 * 2);
    unsigned short* hhi = (unsigned short*)alloc((size_t)n * 256 * 2);
    unsigned short* hlo = (unsigned short*)alloc((size_t)n * 256 * 2);
    unsigned short* W00h = (unsigned short*)alloc(256 * 256 * 2);
    unsigned short* W00l = (unsigned short*)alloc(256 * 256 * 2);
    unsigned short* W01h = (unsigned short*)alloc(256 * 64 * 2);
    unsigned short* W01l = (unsigned short*)alloc(256 * 64 * 2);
    unsigned short* W0fh = (unsigned short*)alloc(64 * 40 * 2);
    unsigned short* W0fl = (unsigned short*)alloc(64 * 40 * 2);
    unsigned short* W10h = (unsigned short*)alloc(256 * 256 * 2);
    unsigned short* W10l = (unsigned short*)alloc(256 * 256 * 2);
    unsigned short* W1fh = (unsigned short*)alloc(256 * 64 * 2);
    unsigned short* W1fl = (unsigned short*)alloc(256 * 64 * 2);
    unsigned short* W1oh = (unsigned short*)alloc(64 * 40 * 2);
    unsigned short* W1ol = (unsigned short*)alloc(64 * 40 * 2);

    // ---- CSR build ----
    hipMemsetAsync(deg, 0, (size_t)n * 4, stream);
    k_hist<<<(e + 255) / 256, 256, 0, stream>>>(dst, deg, e);
    int nb = (n + 1023) / 1024;
    k_scan1<<<nb, 1024, 0, stream>>>(deg, tmp, bsum, n);
    k_scan2<<<1, 1, 0, stream>>>(bsum, nb);
    k_scan3<<<(n + 255) / 256, 256, 0, stream>>>(deg, tmp, bsum, rowptr, cursor, n);
    k_scatter<<<(e + 255) / 256, 256, 0, stream>>>(src, dst, cursor, csr, e);

    // ---- casts ----
    int nel = n * 256;
    k_castx<<<(nel + 255) / 256, 256, 0, stream>>>(x, xhi, xlo, nel);
    k_castw<<<(256 * 256 + 255) / 256, 256, 0, stream>>>(W00, W00h, W00l, 256, 256);
    k_castw<<<(256 * 64 + 255) / 256, 256, 0, stream>>>(W01, W01h, W01l, 256, 64);
    k_castw<<<(64 * 40 + 255) / 256, 256, 0, stream>>>(W0f, W0fh, W0fl, 64, 40);
    k_castw<<<(256 * 256 + 255) / 256, 256, 0, stream>>>(W10, W10h, W10l, 256, 256);
    k_castw<<<(256 * 64 + 255) / 256, 256, 0, stream>>>(W1f, W1fh, W1fl, 256, 64);
    k_castw<<<(64 * 40 + 255) / 256, 256, 0, stream>>>(W1o, W1oh, W1ol, 64, 40);

    int gw4 = (n * 4 + 3) / 4;
    int gw1 = (n + 3) / 4;

    // ---- branch 0 ----
    gemm_split(xhi, xlo, W00h, W00l, feat, n, 256, 256, stream);
    k_attn<4, 64><<<gw4, 256, 0, stream>>>(feat, a00l, a00r, el, er, n);
    k_agg4<1, 1><<<n, 256, 0, stream>>>(rowptr, csr, el, er, feat, hhi, hlo, nullptr, n);

    gemm_split(hhi, hlo, W01h, W01l, feat, n, 64, 256, stream);
    k_attn<1, 64><<<gw1, 256, 0, stream>>>(feat, a01l, a01r, el, er, n);
    k_agg1<64, 1, 1><<<gw1, 256, 0, stream>>>(rowptr, csr, el, er, feat, hhi, hlo, nullptr, n);

    gemm_split(hhi, hlo, W0fh, W0fl, feat, n, C, 64, stream);
    k_attn<1, 40><<<gw1, 256, 0, stream>>>(feat, a0fl, a0fr, el, er, n);
    k_agg1<40, 0, 0><<<gw1, 256, 0, stream>>>(rowptr, csr, el, er, feat, nullptr, nullptr, out, n);

    // ---- branch 1 ----
    gemm_split(xhi, xlo, W10h, W10l, feat, n, 256, 256, stream);
    k_attn<4, 64><<<gw4, 256, 0, stream>>>(feat, a10l, a10r, el, er, n);
    k_agg4<1, 1><<<n, 256, 0, stream>>>(rowptr, csr, el, er, feat, hhi, hlo, nullptr, n);

    gemm_split(hhi, hlo, W1fh, W1fl, feat, n, 64, 256, stream);
    k_attn<1, 64><<<gw1, 256, 0, stream>>>(feat, a1fl, a1fr, el, er, n);
    k_agg1<64, 0, 1><<<gw1, 256, 0, stream>>>(rowptr, csr, el, er, feat, hhi, hlo, nullptr, n);

    gemm_split(hhi, hlo, W1oh, W1ol, feat, n, C, 64, stream);
    k_attn<1, 40><<<gw1, 256, 0, stream>>>(feat, a1ol, a1or, el, er, n);
    k_agg1<40, 1, 0><<<gw1, 256, 0, stream>>>(rowptr, csr, el, er, feat, nullptr, nullptr,
                                              out + (size_t)n * C, n);
}